// Round 4
// baseline (306.870 us; speedup 1.0000x reference)
//
#include <hip/hip_runtime.h>
#include <math.h>

typedef _Float16 f16;
typedef __attribute__((ext_vector_type(8)))  _Float16 f16v8;
typedef __attribute__((ext_vector_type(16))) float    f32x16;
typedef __attribute__((ext_vector_type(4)))  float    f32x4;

namespace {
constexpr int kB = 64, kCin = 512, kT = 1024, kCout = 256;
constexpr size_t kYBytes     = (size_t)kB * kT * kCout * 4;    // 64 MiB y buffer ([b][o][t])
constexpr size_t kWfragBytes = (size_t)32 * 8 * 2 * 64 * 16;   // 512 KiB [kc][osub][plane][lane][16B]
constexpr size_t kSBytes     = kCout * 4;
constexpr size_t kWsNeed     = kYBytes + kWfragBytes + kSBytes;
}

// ---- prep: W' = 32*W split into 2 f16 planes (low plane scaled 2^11), A-frag order ----
// A-frag (32x32x16): m(o) = lane&31, k = (lane>>5)*8 + j.  Block (0,0,0) also fills sarr.
__global__ void wsplit16_kernel(const float* __restrict__ W, const float* __restrict__ gamma,
                                const float* __restrict__ rvar,
                                f16* __restrict__ wfrag, float* __restrict__ sarr) {
    const int kc = blockIdx.x, osub = blockIdx.y, p = blockIdx.z;
    const int lane = threadIdx.x;
    const int o  = osub * 32 + (lane & 31);
    const int kb = kc * 16 + (lane >> 5) * 8;
    f16v8 frag;
#pragma unroll
    for (int j = 0; j < 8; ++j) {
        const float w = 32.0f * W[o * kCin + kb + j];   // 2^5 pre-scale (denorm guard)
        const f16 h = (f16)w;                           // RNE
        const float r = w - (float)h;                   // exact
        const f16 l = (f16)(r * 2048.0f);               // low plane scaled 2^11
        frag[j] = p ? l : h;
    }
    *reinterpret_cast<f16v8*>(wfrag + ((size_t)((kc * 8 + osub) * 2 + p) * 64 + lane) * 8) = frag;
    if (kc == 0 && osub == 0 && p == 0) {
#pragma unroll
        for (int j = 0; j < 4; ++j) {
            const int oo = j * 64 + lane;
            sarr[oo] = (float)((double)gamma[oo] / sqrt((double)rvar[oo] + 1e-5));
        }
    }
}

// ---- GEMM: f16 2-plane MFMA, ZERO LDS / ZERO barriers — fully independent waves ----
// Rationale (R1/R2/R3 counters): duration was invariant to waves-per-SIMD inside a
// barrier-coupled block (R1 87us @ 8 waves/CU == R3 91us @ 16 waves/CU), while
// independent blocks helped (R2). Matrix pipes are 5.6% busy; the limiter is the
// block-wide lgkm+barrier lockstep. The mfma B-frag is per-lane loadable: lane(n,q)
// needs x[k=q*8+j][t=tg0+s*32+n], j=0..7 — 8 coalesced dword loads per s. So each
// wave loads its own x-tile and converts the 2 f16 planes in-register (identical
// per-element ops as the old stage(): RTZ pack + (x-h)*2048 → bit-identical y).
// Grid (32, 64): bx = (tchunk<<1)|ohalf so the two blocks sharing an x-tile are
// dispatch-adjacent (same-time, L2/L3-hot re-read — avoids R2's fetch blowup).
// Wave w: osub = ohalf*4+w (32o), full 64t (2 tsub). acc 64 AGPR; x dbuf 32 VGPR;
// ~146 regs -> launch_bounds(256,3): 12 independent waves/CU, no sync anywhere.
__global__ __launch_bounds__(256, 3)
void gemm_f16_kernel(const float* __restrict__ x, const f16* __restrict__ wfrag,
                     const float* __restrict__ sarr, const float* __restrict__ rmean,
                     const float* __restrict__ beta, float* __restrict__ yt) {
    const int tid  = threadIdx.x;
    const int lane = tid & 63;
    const int wave = tid >> 6;
    const int n = lane & 31, q = lane >> 5;
    const int b   = blockIdx.y;
    const int tg0 = (blockIdx.x >> 1) * 64;
    const int osg = (blockIdx.x & 1) * 4 + wave;            // global osub 0..7
    const float* __restrict__ xb = x + ((size_t)b << 19);   // b*512*1024
    const f16v8* __restrict__ wf = reinterpret_cast<const f16v8*>(wfrag);

    // per-lane x base pointers: row q*8, col tg0+n (s=0) / +32 (s=1)
    const float* __restrict__ xp0 = xb + (size_t)(q * 8) * kT + tg0 + n;
    const float* __restrict__ xp1 = xp0 + 32;

    f32x16 accA[2] = {};   // [tsub] hh
    f32x16 accB[2] = {};   // [tsub] cross (scaled 2^11)
    f16v8  af[2][2];       // [buf][plane]
    float  xr[2][2][8];    // [buf][tsub][j] raw x, double-buffered

    auto loadX = [&](int kc, float (&xd)[2][8]) {
        const float* p0 = xp0 + (size_t)kc * 16 * kT;
        const float* p1 = xp1 + (size_t)kc * 16 * kT;
#pragma unroll
        for (int j = 0; j < 8; ++j) {
            xd[0][j] = p0[(size_t)j * kT];   // 64 lanes = rows {q*8+j}, 2x128B segments
            xd[1][j] = p1[(size_t)j * kT];
        }
    };
    auto loadA = [&](int kc, f16v8 (&ad)[2]) {
#pragma unroll
        for (int p = 0; p < 2; ++p)
            ad[p] = wf[(size_t)((kc * 8 + osg) * 2 + p) * 64 + lane];
    };
    // convert raw x -> (high, low) f16 planes; same per-element ops as old stage()
    auto convert = [&](const float (&xd)[2][8], f16v8 (&bh)[2], f16v8 (&bl)[2]) {
#pragma unroll
        for (int s = 0; s < 2; ++s)
#pragma unroll
            for (int jj = 0; jj < 4; ++jj) {
                auto h = __builtin_amdgcn_cvt_pkrtz(xd[s][2 * jj], xd[s][2 * jj + 1]);
                auto l = __builtin_amdgcn_cvt_pkrtz((xd[s][2 * jj]     - (float)h[0]) * 2048.0f,
                                                    (xd[s][2 * jj + 1] - (float)h[1]) * 2048.0f);
                bh[s][2 * jj] = h[0]; bh[s][2 * jj + 1] = h[1];
                bl[s][2 * jj] = l[0]; bl[s][2 * jj + 1] = l[1];
            }
    };
    auto domfma = [&](const f16v8 (&ad)[2], const f16v8 (&bh)[2], const f16v8 (&bl)[2]) {
        __builtin_amdgcn_s_setprio(1);
#pragma unroll
        for (int s = 0; s < 2; ++s) {
            accA[s] = __builtin_amdgcn_mfma_f32_32x32x16_f16(ad[0], bh[s], accA[s], 0, 0, 0);
            accB[s] = __builtin_amdgcn_mfma_f32_32x32x16_f16(ad[0], bl[s], accB[s], 0, 0, 0);
            accB[s] = __builtin_amdgcn_mfma_f32_32x32x16_f16(ad[1], bh[s], accB[s], 0, 0, 0);
        }
        __builtin_amdgcn_s_setprio(0);
    };

    loadX(0, xr[0]);
    loadA(0, af[0]);
    for (int kc2 = 0; kc2 < 16; ++kc2) {
#pragma unroll
        for (int u = 0; u < 2; ++u) {
            const int kc = kc2 * 2 + u;
            if (kc < 31) {                      // prefetch next chunk (distance 1)
                loadX(kc + 1, xr[(u + 1) & 1]);
                loadA(kc + 1, af[(u + 1) & 1]);
            }
            f16v8 bh[2], bl[2];
            convert(xr[u & 1], bh, bl);         // compiler inserts vmcnt wait here
            domfma(af[u & 1], bh, bl);
        }
    }

    // ---- epilogue: combine planes, BN affine, store yt[b][o][t] (no LDS) ----
    // C/D: col(t)=lane&31, row(o)=(reg&3)+8*(reg>>2)+4*(lane>>5)
#pragma unroll
    for (int s = 0; s < 2; ++s) {
        const f32x16 v = accA[s] + accB[s] * 4.8828125e-4f;   // + cross/2^11
        const size_t t = (size_t)tg0 + s * 32 + n;
#pragma unroll
        for (int g = 0; g < 4; ++g) {
            const int og = osg * 32 + g * 8 + q * 4;
            const f32x4 sv = *reinterpret_cast<const f32x4*>(sarr + og);
            const f32x4 mv = *reinterpret_cast<const f32x4*>(rmean + og);
            const f32x4 bv = *reinterpret_cast<const f32x4*>(beta + og);
#pragma unroll
            for (int r2 = 0; r2 < 4; ++r2) {
                const int o = og + r2;
                // exact /32 un-scale, then BN (same per-element op order as before)
                const float val = (v[4 * g + r2] * 0.03125f - mv[r2]) * sv[r2] + bv[r2];
                yt[(((size_t)b << 8) + (size_t)o) * 1024 + t] = val;
            }
        }
    }
}

// ---- LIF: one wave per (b, 64-o slice); yt[b][o][t] rows are contiguous ----
// Each lane owns one o-chain and reads float4 over t (16-quad static prefetch
// queue, 16 KiB/wave in flight). Bit-exact fp32 recurrence vs reference.
__global__ __launch_bounds__(64)
void lif_kernel(const float* __restrict__ yt, float* __restrict__ out) {
    const int b = blockIdx.x >> 2;
    const int o = ((blockIdx.x & 3) << 6) + threadIdx.x;
    const f32x4* __restrict__ row =
        reinterpret_cast<const f32x4*>(yt) + (((size_t)b << 8) + (size_t)o) * 256;
    float v = 0.f;
    int cnt = 0;
    f32x4 qb[16];
#pragma unroll
    for (int u = 0; u < 16; ++u) qb[u] = row[u];
    for (int jj = 0; jj < 15; ++jj) {
#pragma unroll
        for (int u = 0; u < 16; ++u) {
            const f32x4 cv = qb[u];
            qb[u] = row[jj * 16 + u + 16];   // distance-16 prefetch, static slot
#pragma unroll
            for (int e = 0; e < 4; ++e) {
                v = v + (cv[e] - v) * 0.5f;             // bit-exact reference recurrence
                if (v - 1.0f >= 0.0f) { ++cnt; v = 0.f; }
            }
        }
    }
#pragma unroll
    for (int u = 0; u < 16; ++u) {
        const f32x4 cv = qb[u];
#pragma unroll
        for (int e = 0; e < 4; ++e) {
            v = v + (cv[e] - v) * 0.5f;
            if (v - 1.0f >= 0.0f) { ++cnt; v = 0.f; }
        }
    }
    out[((size_t)b << 8) + o] = (float)cnt * (1.0f / 1024.0f);
}

// ---- fallback (round-1 fp32 fused path, unchanged) ----
namespace fb {
constexpr int kOTile = 32, kTTile = 128, kCc = 64;
constexpr int kNtt = kT / kTTile, kNcc = kCin / kCc, kYPad = 132;
}

__global__ void wt_transpose_kernel(const float* __restrict__ W, float* __restrict__ Wt) {
    int idx = blockIdx.x * 256 + threadIdx.x;
    int c = idx >> 8, o = idx & 255;
    Wt[idx] = W[o * kCin + c];
}

__global__ __launch_bounds__(256, 2)
void snn_fused_kernel(const float* __restrict__ x, const float* __restrict__ Wt,
                      const float* __restrict__ gamma, const float* __restrict__ beta,
                      const float* __restrict__ rmean, const float* __restrict__ rvar,
                      float* __restrict__ out) {
    using namespace fb;
    __shared__ float xs[kCc][kTTile];
    __shared__ float ws[kCc][kOTile];
    __shared__ float ytile[kOTile][kYPad];
    __shared__ float sarr[kOTile], barr[kOTile], marr[kOTile], vstate[kOTile];
    __shared__ int scnt[kOTile];
    const int tid = threadIdx.x, tx = tid & 31, ty = tid >> 5;
    const int b = blockIdx.y, o_blk = blockIdx.x * kOTile;
    if (tid < kOTile) {
        const int o = o_blk + tid;
        const double dinv = 1.0 / sqrt((double)rvar[o] + 1e-5);
        sarr[tid] = (float)(dinv * (double)gamma[o]);
        barr[tid] = beta[o]; marr[tid] = rmean[o];
        vstate[tid] = 0.0f; scnt[tid] = 0;
    }
    __syncthreads();
    const float* xb = x + (size_t)b * kCin * kT;
    for (int tt = 0; tt < kNtt; ++tt) {
        float acc[4][4];
#pragma unroll
        for (int i = 0; i < 4; ++i)
#pragma unroll
            for (int j = 0; j < 4; ++j) acc[i][j] = 0.0f;
        const int t0 = tt * kTTile;
        for (int cc = 0; cc < kNcc; ++cc) {
#pragma unroll
            for (int k = 0; k < 8; ++k) {
                const int f = tid + 256 * k;
                const int c = f >> 5, tq = f & 31;
                *reinterpret_cast<float4*>(&xs[c][tq * 4]) = *reinterpret_cast<const float4*>(
                    xb + (size_t)(cc * kCc + c) * kT + t0 + tq * 4);
            }
#pragma unroll
            for (int k = 0; k < 2; ++k) {
                const int f = tid + 256 * k;
                const int c = f >> 3, oq = f & 7;
                *reinterpret_cast<float4*>(&ws[c][oq * 4]) = *reinterpret_cast<const float4*>(
                    Wt + (size_t)(cc * kCc + c) * kCout + o_blk + oq * 4);
            }
            __syncthreads();
#pragma unroll 8
            for (int c = 0; c < kCc; ++c) {
                const float4 xv = *reinterpret_cast<const float4*>(&xs[c][tx * 4]);
                const float4 wv = *reinterpret_cast<const float4*>(&ws[c][ty * 4]);
                const float xf[4] = {xv.x, xv.y, xv.z, xv.w};
                const float wf4[4] = {wv.x, wv.y, wv.z, wv.w};
#pragma unroll
                for (int i = 0; i < 4; ++i)
#pragma unroll
                    for (int j = 0; j < 4; ++j) acc[i][j] += wf4[i] * xf[j];
            }
            __syncthreads();
        }
#pragma unroll
        for (int i = 0; i < 4; ++i) {
            const int o = ty * 4 + i;
            const float s = sarr[o], bb2 = barr[o], m = marr[o];
#pragma unroll
            for (int j = 0; j < 4; ++j) ytile[o][tx * 4 + j] = (acc[i][j] - m) * s + bb2;
        }
        __syncthreads();
        if (tid < kOTile) {
            float vv = vstate[tid];
            int cnt = 0;
#pragma unroll 4
            for (int t = 0; t < kTTile; ++t) {
                const float yv = ytile[tid][t];
                vv = vv + (yv - vv) * 0.5f;
                if (vv - 1.0f >= 0.0f) { cnt++; vv = 0.0f; }
            }
            vstate[tid] = vv; scnt[tid] += cnt;
        }
        __syncthreads();
    }
    if (tid < kOTile) out[b * kCout + o_blk + tid] = (float)scnt[tid] * (1.0f / 1024.0f);
}

extern "C" void kernel_launch(void* const* d_in, const int* in_sizes, int n_in,
                              void* d_out, int out_size, void* d_ws, size_t ws_size,
                              hipStream_t stream) {
    const float* x     = (const float*)d_in[0];
    const float* W     = (const float*)d_in[1];
    const float* gamma = (const float*)d_in[2];
    const float* beta  = (const float*)d_in[3];
    const float* rmean = (const float*)d_in[4];
    const float* rvar  = (const float*)d_in[5];
    float* out = (float*)d_out;

    if (ws_size >= kWsNeed) {
        float* yt    = (float*)d_ws;
        f16*   wfrag = (f16*)((char*)d_ws + kYBytes);
        float* sarr  = (float*)((char*)d_ws + kYBytes + kWfragBytes);
        wsplit16_kernel<<<dim3(32, 8, 2), 64, 0, stream>>>(W, gamma, rvar, wfrag, sarr);
        gemm_f16_kernel<<<dim3(32, 64), 256, 0, stream>>>(x, wfrag, sarr, rmean, beta, yt);
        lif_kernel<<<256, 64, 0, stream>>>(yt, out);
    } else {
        float* Wt = (float*)d_ws;
        wt_transpose_kernel<<<(kCin * kCout) / 256, 256, 0, stream>>>(W, Wt);
        snn_fused_kernel<<<dim3(kCout / fb::kOTile, kB), 256, 0, stream>>>(
            x, Wt, gamma, beta, rmean, rvar, out);
    }
}

// Round 6
// 285.283 us; speedup vs baseline: 1.0757x; 1.0757x over previous
//
#include <hip/hip_runtime.h>
#include <math.h>

typedef _Float16 f16;
typedef __attribute__((ext_vector_type(8)))  _Float16 f16v8;
typedef __attribute__((ext_vector_type(16))) float    f32x16;
typedef __attribute__((ext_vector_type(4)))  float    f32x4;

namespace {
constexpr int kB = 64, kCin = 512, kT = 1024, kCout = 256;
constexpr size_t kYBytes     = (size_t)kB * kT * kCout * 4;    // 64 MiB y buffer ([b][o][t])
constexpr size_t kWfragBytes = (size_t)32 * 8 * 2 * 64 * 16;   // 512 KiB [kc][osub][plane][lane][16B]
constexpr size_t kSBytes     = kCout * 4;
constexpr size_t kWsNeed     = kYBytes + kWfragBytes + kSBytes;
}

// global_load_lds helper: LDS dest is wave-uniform base (HW adds lane*SZ);
// global src is per-lane. The builtin's size arg must be a LITERAL constant
// (template param doesn't qualify) -> if constexpr dispatch.
template <int SZ>
__device__ __forceinline__ void glds(const void* gsrc, void* lds) {
    auto g = (const __attribute__((address_space(1))) unsigned int*)gsrc;
    auto l = (__attribute__((address_space(3))) unsigned int*)lds;
    if constexpr (SZ == 16) {
        __builtin_amdgcn_global_load_lds(g, l, 16, 0, 0);
    } else if constexpr (SZ == 4) {
        __builtin_amdgcn_global_load_lds(g, l, 4, 0, 0);
    }
}

// ---- prep: W' = 32*W split into 2 f16 planes (low plane scaled 2^11), A-frag order ----
// A-frag (32x32x16): m(o) = lane&31, k = (lane>>5)*8 + j.  Block (0,0,0) also fills sarr.
// Layout per chunk kc: 16 KiB, [osub=8][plane=2][lane=64][16B] -> glds-linear.
__global__ void wsplit16_kernel(const float* __restrict__ W, const float* __restrict__ gamma,
                                const float* __restrict__ rvar,
                                f16* __restrict__ wfrag, float* __restrict__ sarr) {
    const int kc = blockIdx.x, osub = blockIdx.y, p = blockIdx.z;
    const int lane = threadIdx.x;
    const int o  = osub * 32 + (lane & 31);
    const int kb = kc * 16 + (lane >> 5) * 8;
    f16v8 frag;
#pragma unroll
    for (int j = 0; j < 8; ++j) {
        const float w = 32.0f * W[o * kCin + kb + j];   // 2^5 pre-scale (denorm guard)
        const f16 h = (f16)w;                           // RNE
        const float r = w - (float)h;                   // exact
        const f16 l = (f16)(r * 2048.0f);               // low plane scaled 2^11
        frag[j] = p ? l : h;
    }
    *reinterpret_cast<f16v8*>(wfrag + ((size_t)((kc * 8 + osub) * 2 + p) * 64 + lane) * 8) = frag;
    if (kc == 0 && osub == 0 && p == 0) {
#pragma unroll
        for (int j = 0; j < 4; ++j) {
            const int oo = j * 64 + lane;
            sarr[oo] = (float)((double)gamma[oo] / sqrt((double)rvar[oo] + 1e-5));
        }
    }
}

// ---- GEMM: f16 2-plane MFMA, ALL global traffic via global_load_lds + counted vmcnt ----
// R1-R4 evidence: dur == hbm_bytes/achieved_BW in every variant (1.47-2.08 TB/s);
// the limiter is compiler-managed vmcnt on register-destination loads draining the
// prefetch queue (effective depth ~1 -> per-chunk HBM-latency stall). Fix (T3+T4):
// zero reg-dest vmem in the K-loop. Per body, each of 8 waves issues exactly
// [W glds16, W glds16, x glds4, x glds4] (W for kc+2, x for kc+3), then
// s_waitcnt vmcnt(10): retains {body kc: 4, body kc-1: 4, x(kc+1): 2} in flight,
// guarantees W(kc), x(kc) landed. Bare s_barrier (no compiler drain). Second bare
// barrier after compute (lgkm(0) first) protects buffer reuse. Tail bodies issue
// wrapped dummy stages to keep vmcnt counts uniform.
// Block: 512 thr = 8 waves, tile 256o x 64t, wave w = osub w; x read ONCE per tile.
// LDS: xs 4 bufs x 4KB (fp32 chunk [16][64]) + ws 3 bufs x 16KB = 64 KiB -> 2 blk/CU.
// Consume: A = 2x ds_read_b128 (lane-linear, wave reads what it staged); x = column
// ds_reads (bank n, 2-way q-alias = free) + identical cvt_pkrtz conversion
// (same value-pairs + same MFMA order as R1-R4 -> bit-identical y).
__global__ __launch_bounds__(512, 4)
void gemm_f16_kernel(const float* __restrict__ x, const f16* __restrict__ wfrag,
                     const float* __restrict__ sarr, const float* __restrict__ rmean,
                     const float* __restrict__ beta, float* __restrict__ yt) {
    __shared__ float xs[4][16][64];     // 16 KiB raw x chunks
    __shared__ f16v8 ws[3][16][64];     // 48 KiB W-frag chunks [buf][instr=osub*2+plane][lane]

    const int tid  = threadIdx.x;
    const int lane = tid & 63;
    const int wave = tid >> 6;          // osub AND staging slice
    const int n = lane & 31, q = lane >> 5;
    const int b   = blockIdx.y;
    const int tg0 = blockIdx.x * 64;
    const float* __restrict__ xb = x + ((size_t)b << 19);   // b*512*1024

    f32x16 accA[2] = {};   // [tsub] hh
    f32x16 accB[2] = {};   // [tsub] cross (scaled 2^11)

    // stage W chunk wkc into ws[wbuf]: wave w -> instrs 2w, 2w+1 (= its own osub, planes 0/1)
    auto stageW = [&](int wkc, int wbuf) {
#pragma unroll
        for (int r = 0; r < 2; ++r)
            glds<16>(wfrag + ((size_t)wkc * 16 + 2 * wave + r) * 512 + lane * 8,
                     (void*)&ws[wbuf][2 * wave + r][0]);
    };
    // stage x chunk xkc into xs[xbuf]: wave w -> rows 2w, 2w+1 (64 lanes x 4B = one row)
    auto stageX = [&](int xkc, int xbuf) {
#pragma unroll
        for (int r = 0; r < 2; ++r)
            glds<4>(xb + (size_t)(16 * xkc + 2 * wave + r) * 1024 + tg0 + lane,
                    (void*)&xs[xbuf][2 * wave + r][0]);
    };

    // prologue bodies (-3,-2,-1): issue-only. Order per wave: [x0 x0][W0 W0 x1 x1][W1 W1 x2 x2]
    stageX(0, 0);
    stageW(0, 0); stageX(1, 1);
    stageW(1, 1); stageX(2, 2);

    int wb3 = 2, cb3 = 0;   // W stage/compute buffers mod 3 (kc=0: stage ws[2], read ws[0])

    for (int kc = 0; kc < 32; ++kc) {
        // ---- stage body: [W,W,x,x] for chunks kc+2 / kc+3 (wrapped dummies at tail) ----
        stageW((kc + 2) & 31, wb3);
        stageX((kc + 3) & 31, (kc + 3) & 3);
        __builtin_amdgcn_sched_barrier(0);
        asm volatile("s_waitcnt vmcnt(10)" ::: "memory");   // W(kc), x(kc) landed; queue stays full
        __builtin_amdgcn_s_barrier();                        // bare: no compiler drain
        __builtin_amdgcn_sched_barrier(0);

        // ---- compute chunk kc from LDS ----
        const int cxb = kc & 3;
        const f16v8 a0 = ws[cb3][2 * wave + 0][lane];   // ds_read_b128, lane-linear
        const f16v8 a1 = ws[cb3][2 * wave + 1][lane];
#pragma unroll
        for (int s = 0; s < 2; ++s) {
            float xe[8];
#pragma unroll
            for (int j = 0; j < 8; ++j) xe[j] = xs[cxb][q * 8 + j][32 * s + n];
            f16v8 bh, bl;
#pragma unroll
            for (int d = 0; d < 4; ++d) {
                auto h = __builtin_amdgcn_cvt_pkrtz(xe[2 * d], xe[2 * d + 1]);   // RTZ pack
                auto l = __builtin_amdgcn_cvt_pkrtz((xe[2 * d]     - (float)h[0]) * 2048.0f,
                                                    (xe[2 * d + 1] - (float)h[1]) * 2048.0f);
                bh[2 * d] = h[0]; bh[2 * d + 1] = h[1];
                bl[2 * d] = l[0]; bl[2 * d + 1] = l[1];
            }
            __builtin_amdgcn_s_setprio(1);
            accA[s] = __builtin_amdgcn_mfma_f32_32x32x16_f16(a0, bh, accA[s], 0, 0, 0);
            accB[s] = __builtin_amdgcn_mfma_f32_32x32x16_f16(a0, bl, accB[s], 0, 0, 0);
            accB[s] = __builtin_amdgcn_mfma_f32_32x32x16_f16(a1, bh, accB[s], 0, 0, 0);
            __builtin_amdgcn_s_setprio(0);
        }

        __builtin_amdgcn_sched_barrier(0);
        asm volatile("s_waitcnt lgkmcnt(0)" ::: "memory");   // all LDS reads done
        __builtin_amdgcn_s_barrier();                        // buffers now reusable
        wb3 = (wb3 == 2) ? 0 : wb3 + 1;
        cb3 = (cb3 == 2) ? 0 : cb3 + 1;
    }

    // ---- epilogue: combine planes, BN affine, store yt[b][o][t] (no LDS) ----
    // C/D: col(t)=lane&31, row(o)=(reg&3)+8*(reg>>2)+4*(lane>>5)
#pragma unroll
    for (int s = 0; s < 2; ++s) {
        const f32x16 v = accA[s] + accB[s] * 4.8828125e-4f;   // + cross/2^11
        const size_t t = (size_t)tg0 + s * 32 + n;
#pragma unroll
        for (int g = 0; g < 4; ++g) {
            const int og = wave * 32 + g * 8 + q * 4;
            const f32x4 sv = *reinterpret_cast<const f32x4*>(sarr + og);
            const f32x4 mv = *reinterpret_cast<const f32x4*>(rmean + og);
            const f32x4 bv = *reinterpret_cast<const f32x4*>(beta + og);
#pragma unroll
            for (int r2 = 0; r2 < 4; ++r2) {
                const int o = og + r2;
                // exact /32 un-scale, then BN (same per-element op order as before)
                const float val = (v[4 * g + r2] * 0.03125f - mv[r2]) * sv[r2] + bv[r2];
                yt[(((size_t)b << 8) + (size_t)o) * 1024 + t] = val;
            }
        }
    }
}

// ---- LIF: one wave per (b, 64-o slice); yt[b][o][t] rows are contiguous ----
// Each lane owns one o-chain and reads float4 over t (16-quad static prefetch
// queue, 16 KiB/wave in flight). Bit-exact fp32 recurrence vs reference.
__global__ __launch_bounds__(64)
void lif_kernel(const float* __restrict__ yt, float* __restrict__ out) {
    const int b = blockIdx.x >> 2;
    const int o = ((blockIdx.x & 3) << 6) + threadIdx.x;
    const f32x4* __restrict__ row =
        reinterpret_cast<const f32x4*>(yt) + (((size_t)b << 8) + (size_t)o) * 256;
    float v = 0.f;
    int cnt = 0;
    f32x4 qb[16];
#pragma unroll
    for (int u = 0; u < 16; ++u) qb[u] = row[u];
    for (int jj = 0; jj < 15; ++jj) {
#pragma unroll
        for (int u = 0; u < 16; ++u) {
            const f32x4 cv = qb[u];
            qb[u] = row[jj * 16 + u + 16];   // distance-16 prefetch, static slot
#pragma unroll
            for (int e = 0; e < 4; ++e) {
                v = v + (cv[e] - v) * 0.5f;             // bit-exact reference recurrence
                if (v - 1.0f >= 0.0f) { ++cnt; v = 0.f; }
            }
        }
    }
#pragma unroll
    for (int u = 0; u < 16; ++u) {
        const f32x4 cv = qb[u];
#pragma unroll
        for (int e = 0; e < 4; ++e) {
            v = v + (cv[e] - v) * 0.5f;
            if (v - 1.0f >= 0.0f) { ++cnt; v = 0.f; }
        }
    }
    out[((size_t)b << 8) + o] = (float)cnt * (1.0f / 1024.0f);
}

// ---- fallback (round-1 fp32 fused path, unchanged) ----
namespace fb {
constexpr int kOTile = 32, kTTile = 128, kCc = 64;
constexpr int kNtt = kT / kTTile, kNcc = kCin / kCc, kYPad = 132;
}

__global__ void wt_transpose_kernel(const float* __restrict__ W, float* __restrict__ Wt) {
    int idx = blockIdx.x * 256 + threadIdx.x;
    int c = idx >> 8, o = idx & 255;
    Wt[idx] = W[o * kCin + c];
}

__global__ __launch_bounds__(256, 2)
void snn_fused_kernel(const float* __restrict__ x, const float* __restrict__ Wt,
                      const float* __restrict__ gamma, const float* __restrict__ beta,
                      const float* __restrict__ rmean, const float* __restrict__ rvar,
                      float* __restrict__ out) {
    using namespace fb;
    __shared__ float xs[kCc][kTTile];
    __shared__ float ws[kCc][kOTile];
    __shared__ float ytile[kOTile][kYPad];
    __shared__ float sarr[kOTile], barr[kOTile], marr[kOTile], vstate[kOTile];
    __shared__ int scnt[kOTile];
    const int tid = threadIdx.x, tx = tid & 31, ty = tid >> 5;
    const int b = blockIdx.y, o_blk = blockIdx.x * kOTile;
    if (tid < kOTile) {
        const int o = o_blk + tid;
        const double dinv = 1.0 / sqrt((double)rvar[o] + 1e-5);
        sarr[tid] = (float)(dinv * (double)gamma[o]);
        barr[tid] = beta[o]; marr[tid] = rmean[o];
        vstate[tid] = 0.0f; scnt[tid] = 0;
    }
    __syncthreads();
    const float* xb = x + (size_t)b * kCin * kT;
    for (int tt = 0; tt < kNtt; ++tt) {
        float acc[4][4];
#pragma unroll
        for (int i = 0; i < 4; ++i)
#pragma unroll
            for (int j = 0; j < 4; ++j) acc[i][j] = 0.0f;
        const int t0 = tt * kTTile;
        for (int cc = 0; cc < kNcc; ++cc) {
#pragma unroll
            for (int k = 0; k < 8; ++k) {
                const int f = tid + 256 * k;
                const int c = f >> 5, tq = f & 31;
                *reinterpret_cast<float4*>(&xs[c][tq * 4]) = *reinterpret_cast<const float4*>(
                    xb + (size_t)(cc * kCc + c) * kT + t0 + tq * 4);
            }
#pragma unroll
            for (int k = 0; k < 2; ++k) {
                const int f = tid + 256 * k;
                const int c = f >> 3, oq = f & 7;
                *reinterpret_cast<float4*>(&ws[c][oq * 4]) = *reinterpret_cast<const float4*>(
                    Wt + (size_t)(cc * kCc + c) * kCout + o_blk + oq * 4);
            }
            __syncthreads();
#pragma unroll 8
            for (int c = 0; c < kCc; ++c) {
                const float4 xv = *reinterpret_cast<const float4*>(&xs[c][tx * 4]);
                const float4 wv = *reinterpret_cast<const float4*>(&ws[c][ty * 4]);
                const float xf[4] = {xv.x, xv.y, xv.z, xv.w};
                const float wf4[4] = {wv.x, wv.y, wv.z, wv.w};
#pragma unroll
                for (int i = 0; i < 4; ++i)
#pragma unroll
                    for (int j = 0; j < 4; ++j) acc[i][j] += wf4[i] * xf[j];
            }
            __syncthreads();
        }
#pragma unroll
        for (int i = 0; i < 4; ++i) {
            const int o = ty * 4 + i;
            const float s = sarr[o], bb2 = barr[o], m = marr[o];
#pragma unroll
            for (int j = 0; j < 4; ++j) ytile[o][tx * 4 + j] = (acc[i][j] - m) * s + bb2;
        }
        __syncthreads();
        if (tid < kOTile) {
            float vv = vstate[tid];
            int cnt = 0;
#pragma unroll 4
            for (int t = 0; t < kTTile; ++t) {
                const float yv = ytile[tid][t];
                vv = vv + (yv - vv) * 0.5f;
                if (vv - 1.0f >= 0.0f) { cnt++; vv = 0.0f; }
            }
            vstate[tid] = vv; scnt[tid] += cnt;
        }
        __syncthreads();
    }
    if (tid < kOTile) out[b * kCout + o_blk + tid] = (float)scnt[tid] * (1.0f / 1024.0f);
}

extern "C" void kernel_launch(void* const* d_in, const int* in_sizes, int n_in,
                              void* d_out, int out_size, void* d_ws, size_t ws_size,
                              hipStream_t stream) {
    const float* x     = (const float*)d_in[0];
    const float* W     = (const float*)d_in[1];
    const float* gamma = (const float*)d_in[2];
    const float* beta  = (const float*)d_in[3];
    const float* rmean = (const float*)d_in[4];
    const float* rvar  = (const float*)d_in[5];
    float* out = (float*)d_out;

    if (ws_size >= kWsNeed) {
        float* yt    = (float*)d_ws;
        f16*   wfrag = (f16*)((char*)d_ws + kYBytes);
        float* sarr  = (float*)((char*)d_ws + kYBytes + kWfragBytes);
        wsplit16_kernel<<<dim3(32, 8, 2), 64, 0, stream>>>(W, gamma, rvar, wfrag, sarr);
        gemm_f16_kernel<<<dim3(16, 64), 512, 0, stream>>>(x, wfrag, sarr, rmean, beta, yt);
        lif_kernel<<<256, 64, 0, stream>>>(yt, out);
    } else {
        float* Wt = (float*)d_ws;
        wt_transpose_kernel<<<(kCin * kCout) / 256, 256, 0, stream>>>(W, Wt);
        snn_fused_kernel<<<dim3(kCout / fb::kOTile, kB), 256, 0, stream>>>(
            x, Wt, gamma, beta, rmean, rvar, out);
    }
}

// Round 7
// 264.308 us; speedup vs baseline: 1.1610x; 1.0794x over previous
//
#include <hip/hip_runtime.h>
#include <math.h>

typedef _Float16 f16;
typedef __attribute__((ext_vector_type(8)))  _Float16 f16v8;
typedef __attribute__((ext_vector_type(4)))  __fp16   h16v4;
typedef __attribute__((ext_vector_type(16))) float    f32x16;
typedef __attribute__((ext_vector_type(4)))  float    f32x4;

namespace {
constexpr int kB = 64, kCin = 512, kT = 1024, kCout = 256;
constexpr size_t kYBytes     = (size_t)kB * kT * kCout * 4;    // 64 MiB y buffer ([b][o][t])
constexpr size_t kWfragBytes = (size_t)32 * 8 * 2 * 64 * 16;   // 512 KiB [kc][osub][plane][lane][16B]
constexpr size_t kSBytes     = kCout * 4;
constexpr size_t kWsNeed     = kYBytes + kWfragBytes + kSBytes;
}

// ---- prep: W' = 32*W split into 2 f16 planes (low plane scaled 2^11), A-frag order ----
// A-frag (32x32x16): m(o) = lane&31, k = (lane>>5)*8 + j.  Block (0,0,0) also fills sarr.
__global__ void wsplit16_kernel(const float* __restrict__ W, const float* __restrict__ gamma,
                                const float* __restrict__ rvar,
                                f16* __restrict__ wfrag, float* __restrict__ sarr) {
    const int kc = blockIdx.x, osub = blockIdx.y, p = blockIdx.z;
    const int lane = threadIdx.x;
    const int o  = osub * 32 + (lane & 31);
    const int kb = kc * 16 + (lane >> 5) * 8;
    f16v8 frag;
#pragma unroll
    for (int j = 0; j < 8; ++j) {
        const float w = 32.0f * W[o * kCin + kb + j];   // 2^5 pre-scale (denorm guard)
        const f16 h = (f16)w;                           // RNE
        const float r = w - (float)h;                   // exact
        const f16 l = (f16)(r * 2048.0f);               // low plane scaled 2^11
        frag[j] = p ? l : h;
    }
    *reinterpret_cast<f16v8*>(wfrag + ((size_t)((kc * 8 + osub) * 2 + p) * 64 + lane) * 8) = frag;
    if (kc == 0 && osub == 0 && p == 0) {
#pragma unroll
        for (int j = 0; j < 4; ++j) {
            const int oo = j * 64 + lane;
            sarr[oo] = (float)((double)gamma[oo] / sqrt((double)rvar[oo] + 1e-5));
        }
    }
}

// ---- GEMM: round-2 engine (best measured BW: 2.08 TB/s, 3-4 indep blocks/CU)
// with XCD-paired grid to kill its x re-fetch. ----
// Block: 256 thr = 4 waves, tile 128o x 64t. Two blocks (h=0/1) share each x-tile.
// R2's z=2 grid put the pair 1024 dispatches apart -> second read missed L2+L3
// (FETCH 70->135 MB). Here: 1-D grid 2048, xcd=bid&7, h=(bid>>3)&1,
// pair=(bid&7)+8*(bid>>4): the pair lands 8 dispatches apart on the SAME XCD
// (default round-robin bid%8) -> h=1's x reads hit that XCD's L2. HBM x fetch 1x.
// Everything else bit-identical to round 2 (verified absmax 0.0).
__global__ __launch_bounds__(256, 4)
void gemm_f16_kernel(const float* __restrict__ x, const f16* __restrict__ wfrag,
                     const float* __restrict__ sarr, const float* __restrict__ rmean,
                     const float* __restrict__ beta, float* __restrict__ yt) {
    __shared__ unsigned int Bd[4][64 * 20];   // [buf][t*20 + 4*slot' + dword], 20 KiB

    const int tid  = threadIdx.x;
    const int lane = tid & 63;
    const int wave = tid >> 6;          // staging k-quad AND osub-within-block
    const int n = lane & 31, q = lane >> 5;

    // XCD-paired decode: pair p -> (tc, b); h = o-half
    const int bid  = blockIdx.x;
    const int h    = (bid >> 3) & 1;
    const int p    = (bid & 7) + 8 * (bid >> 4);
    const int b    = p >> 4;
    const int tg0  = (p & 15) * 64;
    const int osg  = h * 4 + wave;                          // global osub 0..7
    const float* __restrict__ xb = x + ((size_t)b << 19);   // b*512*1024
    const f16v8* __restrict__ wf = reinterpret_cast<const f16v8*>(wfrag);

    const int st_t = tid & 63;
    const int kpp  = wave;              // k-quad index 0..3 (k = 4*kpp..4*kpp+3)
    const int st_sw = (st_t >> 3) & 3;
    const int wr_base = 20 * st_t + 2 * (kpp & 1);
    const int s0 = ((0 + (kpp >> 1)) ^ st_sw) * 4;   // plane0 slot offset (dwords)
    const int s1 = ((2 + (kpp >> 1)) ^ st_sw) * 4;   // plane1 slot offset

    f32x16 accA[2] = {};   // [tsub] hh
    f32x16 accB[2] = {};   // [tsub] cross (scaled 2^11)
    f16v8  af[2][2];       // [buf][plane]
    float  xq[4][4];       // [slot][r] 4-deep x prefetch queue

    auto loadX = [&](int kc, float (&xd)[4]) {
        const float* px = xb + (size_t)(kc * 16 + 4 * kpp) * kT + tg0 + st_t;
#pragma unroll
        for (int r = 0; r < 4; ++r) xd[r] = px[(size_t)r * kT];
    };
    auto loadA = [&](int kc, f16v8 (&ad)[2]) {
#pragma unroll
        for (int pp = 0; pp < 2; ++pp)
            ad[pp] = wf[(size_t)((kc * 8 + osg) * 2 + pp) * 64 + lane];
    };
    auto stage = [&](int buf, const float (&xd)[4]) {
        auto h01 = __builtin_amdgcn_cvt_pkrtz(xd[0], xd[1]);   // RTZ pack
        auto h23 = __builtin_amdgcn_cvt_pkrtz(xd[2], xd[3]);
        auto l01 = __builtin_amdgcn_cvt_pkrtz((xd[0] - (float)h01[0]) * 2048.0f,
                                              (xd[1] - (float)h01[1]) * 2048.0f);
        auto l23 = __builtin_amdgcn_cvt_pkrtz((xd[2] - (float)h23[0]) * 2048.0f,
                                              (xd[3] - (float)h23[1]) * 2048.0f);
        h16v4 hv, lv;
        hv[0] = h01[0]; hv[1] = h01[1]; hv[2] = h23[0]; hv[3] = h23[1];
        lv[0] = l01[0]; lv[1] = l01[1]; lv[2] = l23[0]; lv[3] = l23[1];
        *reinterpret_cast<h16v4*>(&Bd[buf][wr_base + s0]) = hv;   // ds_write_b64
        *reinterpret_cast<h16v4*>(&Bd[buf][wr_base + s1]) = lv;
    };
    auto domfma = [&](int buf, const f16v8 (&ad)[2]) {
        __builtin_amdgcn_s_setprio(1);
#pragma unroll
        for (int s = 0; s < 2; ++s) {
            const int t = s * 32 + n;
            const int sw = (t >> 3) & 3;
            const f16v8 bh = *reinterpret_cast<const f16v8*>(&Bd[buf][20 * t + 4 * ((0 + q) ^ sw)]);
            const f16v8 bl = *reinterpret_cast<const f16v8*>(&Bd[buf][20 * t + 4 * ((2 + q) ^ sw)]);
            accA[s] = __builtin_amdgcn_mfma_f32_32x32x16_f16(ad[0], bh, accA[s], 0, 0, 0);
            accB[s] = __builtin_amdgcn_mfma_f32_32x32x16_f16(ad[0], bl, accB[s], 0, 0, 0);
            accB[s] = __builtin_amdgcn_mfma_f32_32x32x16_f16(ad[1], bh, accB[s], 0, 0, 0);
        }
        __builtin_amdgcn_s_setprio(0);
    };

    // prologue: fill 4-deep x queue, A buf 0, stage chunks 0 and 1
    loadX(0, xq[0]); loadX(1, xq[1]); loadX(2, xq[2]); loadX(3, xq[3]);
    loadA(0, af[0]);
    stage(0, xq[0]);
    stage(1, xq[1]);
    asm volatile("s_waitcnt lgkmcnt(0)\n\ts_barrier" ::: "memory");

    for (int kc4 = 0; kc4 < 8; ++kc4) {
#pragma unroll
        for (int u = 0; u < 4; ++u) {
            const int kc = kc4 * 4 + u;
            // all buffer/slot indices below are compile-time: kc&3==u, kc&1==u&1
            if (kc < 31) loadA(kc + 1, af[(u + 1) & 1]);
            if (kc < 30) stage((u + 2) & 3, xq[(u + 2) & 3]);   // stage chunk kc+2
            if (kc < 28) loadX(kc + 4, xq[u]);                  // refill slot
            domfma(u, af[u & 1]);
            if (u & 1)  // one barrier per 2 chunks; global loads stay in flight
                asm volatile("s_waitcnt lgkmcnt(0)\n\ts_barrier" ::: "memory");
        }
    }

    // ---- epilogue: combine planes, BN affine, store yt[b][o][t] (no LDS) ----
    // C/D: col(t)=lane&31, row(o)=(reg&3)+8*(reg>>2)+4*(lane>>5)
#pragma unroll
    for (int s = 0; s < 2; ++s) {
        const f32x16 v = accA[s] + accB[s] * 4.8828125e-4f;   // + cross/2^11
        const size_t t = (size_t)tg0 + s * 32 + n;
#pragma unroll
        for (int g = 0; g < 4; ++g) {
            const int og = osg * 32 + g * 8 + q * 4;
            const f32x4 sv = *reinterpret_cast<const f32x4*>(sarr + og);
            const f32x4 mv = *reinterpret_cast<const f32x4*>(rmean + og);
            const f32x4 bv = *reinterpret_cast<const f32x4*>(beta + og);
#pragma unroll
            for (int r2 = 0; r2 < 4; ++r2) {
                const int o = og + r2;
                // exact /32 un-scale, then BN (same per-element op order as before)
                const float val = (v[4 * g + r2] * 0.03125f - mv[r2]) * sv[r2] + bv[r2];
                yt[(((size_t)b << 8) + (size_t)o) * 1024 + t] = val;
            }
        }
    }
}

// ---- LIF: one wave per (b, 64-o slice); yt[b][o][t] rows are contiguous ----
// Each lane owns one o-chain and reads float4 over t (16-quad static prefetch
// queue, 16 KiB/wave in flight). Bit-exact fp32 recurrence vs reference.
__global__ __launch_bounds__(64)
void lif_kernel(const float* __restrict__ yt, float* __restrict__ out) {
    const int b = blockIdx.x >> 2;
    const int o = ((blockIdx.x & 3) << 6) + threadIdx.x;
    const f32x4* __restrict__ row =
        reinterpret_cast<const f32x4*>(yt) + (((size_t)b << 8) + (size_t)o) * 256;
    float v = 0.f;
    int cnt = 0;
    f32x4 qb[16];
#pragma unroll
    for (int u = 0; u < 16; ++u) qb[u] = row[u];
    for (int jj = 0; jj < 15; ++jj) {
#pragma unroll
        for (int u = 0; u < 16; ++u) {
            const f32x4 cv = qb[u];
            qb[u] = row[jj * 16 + u + 16];   // distance-16 prefetch, static slot
#pragma unroll
            for (int e = 0; e < 4; ++e) {
                v = v + (cv[e] - v) * 0.5f;             // bit-exact reference recurrence
                if (v - 1.0f >= 0.0f) { ++cnt; v = 0.f; }
            }
        }
    }
#pragma unroll
    for (int u = 0; u < 16; ++u) {
        const f32x4 cv = qb[u];
#pragma unroll
        for (int e = 0; e < 4; ++e) {
            v = v + (cv[e] - v) * 0.5f;
            if (v - 1.0f >= 0.0f) { ++cnt; v = 0.f; }
        }
    }
    out[((size_t)b << 8) + o] = (float)cnt * (1.0f / 1024.0f);
}

// ---- fallback (round-1 fp32 fused path, unchanged) ----
namespace fb {
constexpr int kOTile = 32, kTTile = 128, kCc = 64;
constexpr int kNtt = kT / kTTile, kNcc = kCin / kCc, kYPad = 132;
}

__global__ void wt_transpose_kernel(const float* __restrict__ W, float* __restrict__ Wt) {
    int idx = blockIdx.x * 256 + threadIdx.x;
    int c = idx >> 8, o = idx & 255;
    Wt[idx] = W[o * kCin + c];
}

__global__ __launch_bounds__(256, 2)
void snn_fused_kernel(const float* __restrict__ x, const float* __restrict__ Wt,
                      const float* __restrict__ gamma, const float* __restrict__ beta,
                      const float* __restrict__ rmean, const float* __restrict__ rvar,
                      float* __restrict__ out) {
    using namespace fb;
    __shared__ float xs[kCc][kTTile];
    __shared__ float ws[kCc][kOTile];
    __shared__ float ytile[kOTile][kYPad];
    __shared__ float sarr[kOTile], barr[kOTile], marr[kOTile], vstate[kOTile];
    __shared__ int scnt[kOTile];
    const int tid = threadIdx.x, tx = tid & 31, ty = tid >> 5;
    const int b = blockIdx.y, o_blk = blockIdx.x * kOTile;
    if (tid < kOTile) {
        const int o = o_blk + tid;
        const double dinv = 1.0 / sqrt((double)rvar[o] + 1e-5);
        sarr[tid] = (float)(dinv * (double)gamma[o]);
        barr[tid] = beta[o]; marr[tid] = rmean[o];
        vstate[tid] = 0.0f; scnt[tid] = 0;
    }
    __syncthreads();
    const float* xb = x + (size_t)b * kCin * kT;
    for (int tt = 0; tt < kNtt; ++tt) {
        float acc[4][4];
#pragma unroll
        for (int i = 0; i < 4; ++i)
#pragma unroll
            for (int j = 0; j < 4; ++j) acc[i][j] = 0.0f;
        const int t0 = tt * kTTile;
        for (int cc = 0; cc < kNcc; ++cc) {
#pragma unroll
            for (int k = 0; k < 8; ++k) {
                const int f = tid + 256 * k;
                const int c = f >> 5, tq = f & 31;
                *reinterpret_cast<float4*>(&xs[c][tq * 4]) = *reinterpret_cast<const float4*>(
                    xb + (size_t)(cc * kCc + c) * kT + t0 + tq * 4);
            }
#pragma unroll
            for (int k = 0; k < 2; ++k) {
                const int f = tid + 256 * k;
                const int c = f >> 3, oq = f & 7;
                *reinterpret_cast<float4*>(&ws[c][oq * 4]) = *reinterpret_cast<const float4*>(
                    Wt + (size_t)(cc * kCc + c) * kCout + o_blk + oq * 4);
            }
            __syncthreads();
#pragma unroll 8
            for (int c = 0; c < kCc; ++c) {
                const float4 xv = *reinterpret_cast<const float4*>(&xs[c][tx * 4]);
                const float4 wv = *reinterpret_cast<const float4*>(&ws[c][ty * 4]);
                const float xf[4] = {xv.x, xv.y, xv.z, xv.w};
                const float wf4[4] = {wv.x, wv.y, wv.z, wv.w};
#pragma unroll
                for (int i = 0; i < 4; ++i)
#pragma unroll
                    for (int j = 0; j < 4; ++j) acc[i][j] += wf4[i] * xf[j];
            }
            __syncthreads();
        }
#pragma unroll
        for (int i = 0; i < 4; ++i) {
            const int o = ty * 4 + i;
            const float s = sarr[o], bb2 = barr[o], m = marr[o];
#pragma unroll
            for (int j = 0; j < 4; ++j) ytile[o][tx * 4 + j] = (acc[i][j] - m) * s + bb2;
        }
        __syncthreads();
        if (tid < kOTile) {
            float vv = vstate[tid];
            int cnt = 0;
#pragma unroll 4
            for (int t = 0; t < kTTile; ++t) {
                const float yv = ytile[tid][t];
                vv = vv + (yv - vv) * 0.5f;
                if (vv - 1.0f >= 0.0f) { cnt++; vv = 0.0f; }
            }
            vstate[tid] = vv; scnt[tid] += cnt;
        }
        __syncthreads();
    }
    if (tid < kOTile) out[b * kCout + o_blk + tid] = (float)scnt[tid] * (1.0f / 1024.0f);
}

extern "C" void kernel_launch(void* const* d_in, const int* in_sizes, int n_in,
                              void* d_out, int out_size, void* d_ws, size_t ws_size,
                              hipStream_t stream) {
    const float* x     = (const float*)d_in[0];
    const float* W     = (const float*)d_in[1];
    const float* gamma = (const float*)d_in[2];
    const float* beta  = (const float*)d_in[3];
    const float* rmean = (const float*)d_in[4];
    const float* rvar  = (const float*)d_in[5];
    float* out = (float*)d_out;

    if (ws_size >= kWsNeed) {
        float* yt    = (float*)d_ws;
        f16*   wfrag = (f16*)((char*)d_ws + kYBytes);
        float* sarr  = (float*)((char*)d_ws + kYBytes + kWfragBytes);
        wsplit16_kernel<<<dim3(32, 8, 2), 64, 0, stream>>>(W, gamma, rvar, wfrag, sarr);
        gemm_f16_kernel<<<dim3(2048), 256, 0, stream>>>(x, wfrag, sarr, rmean, beta, yt);
        lif_kernel<<<256, 64, 0, stream>>>(yt, out);
    } else {
        float* Wt = (float*)d_ws;
        wt_transpose_kernel<<<(kCin * kCout) / 256, 256, 0, stream>>>(W, Wt);
        snn_fused_kernel<<<dim3(kCout / fb::kOTile, kB), 256, 0, stream>>>(
            x, Wt, gamma, beta, rmean, rvar, out);
    }
}

// Round 8
// 244.342 us; speedup vs baseline: 1.2559x; 1.0817x over previous
//
#include <hip/hip_runtime.h>
#include <math.h>

typedef _Float16 f16;
typedef __attribute__((ext_vector_type(8)))  _Float16 f16v8;
typedef __attribute__((ext_vector_type(4)))  __fp16   h16v4;
typedef __attribute__((ext_vector_type(16))) float    f32x16;
typedef __attribute__((ext_vector_type(4)))  float    f32x4;

namespace {
constexpr int kB = 64, kCin = 512, kT = 1024, kCout = 256;
constexpr size_t kYBytes     = (size_t)kB * kT * kCout * 4;    // 64 MiB y buffer ([b][o][t])
constexpr size_t kWfragBytes = (size_t)32 * 8 * 2 * 64 * 16;   // 512 KiB [kc][osub][plane][lane][16B]
constexpr size_t kSBytes     = kCout * 4;
constexpr size_t kWsNeed     = kYBytes + kWfragBytes + kSBytes;
}

// ---- prep: W' = 32*W split into 2 f16 planes (low plane scaled 2^11), A-frag order ----
// A-frag (32x32x16): m(o) = lane&31, k = (lane>>5)*8 + j.  Block (0,0,0) also fills sarr.
__global__ void wsplit16_kernel(const float* __restrict__ W, const float* __restrict__ gamma,
                                const float* __restrict__ rvar,
                                f16* __restrict__ wfrag, float* __restrict__ sarr) {
    const int kc = blockIdx.x, osub = blockIdx.y, p = blockIdx.z;
    const int lane = threadIdx.x;
    const int o  = osub * 32 + (lane & 31);
    const int kb = kc * 16 + (lane >> 5) * 8;
    f16v8 frag;
#pragma unroll
    for (int j = 0; j < 8; ++j) {
        const float w = 32.0f * W[o * kCin + kb + j];   // 2^5 pre-scale (denorm guard)
        const f16 h = (f16)w;                           // RNE
        const float r = w - (float)h;                   // exact
        const f16 l = (f16)(r * 2048.0f);               // low plane scaled 2^11
        frag[j] = p ? l : h;
    }
    *reinterpret_cast<f16v8*>(wfrag + ((size_t)((kc * 8 + osub) * 2 + p) * 64 + lane) * 8) = frag;
    if (kc == 0 && osub == 0 && p == 0) {
#pragma unroll
        for (int j = 0; j < 4; ++j) {
            const int oo = j * 64 + lane;
            sarr[oo] = (float)((double)gamma[oo] / sqrt((double)rvar[oo] + 1e-5));
        }
    }
}

// ---- GEMM: f16 2-plane MFMA, BT=128 wide-t tile (request-volume-minimizing) ----
// R1-R7 analysis: duration tracks TOTAL global-request volume (x + W-frags + y,
// incl. L2 hits) at a near-constant ~8-12 TB/s service rate, regardless of
// barrier/pipeline structure. Biggest term: W-frags re-read per 64t tile
// (512 KB x 1024 tiles = 512 MB). This kernel doubles the t-tile to 128:
// tiles 1024->512, W traffic 512->256 MB, total volume 724->462 MB.
// Block: 512 thr = 8 waves, tile 256o x 128t; wave w = osub w (32o) x 128t
// (4 tsub): acc = 8 x f32x16 = 128 AGPR. LDS Bd = 4 bufs x 128t x 20dw = 40 KiB.
// Staging/read/swizzle math identical to the verified R2/R7 engine (st_t now
// 0..127, kpp = tid>>7 in 0..3); barrier (lgkm-only) per 2 chunks; per-element
// arithmetic and K-order unchanged -> bit-identical y.
__global__ __launch_bounds__(512, 2)
void gemm_f16_kernel(const float* __restrict__ x, const f16* __restrict__ wfrag,
                     const float* __restrict__ sarr, const float* __restrict__ rmean,
                     const float* __restrict__ beta, float* __restrict__ yt) {
    __shared__ unsigned int Bd[4][128 * 20];   // [buf][t*20 + 4*slot' + dword], 40 KiB

    const int tid  = threadIdx.x;
    const int lane = tid & 63;
    const int wave = tid >> 6;          // 0..7: osub (compute)
    const int n = lane & 31, q = lane >> 5;
    const int b   = blockIdx.y;
    const int tg0 = blockIdx.x * 128;
    const int osg = wave;                                   // global osub 0..7
    const float* __restrict__ xb = x + ((size_t)b << 19);   // b*512*1024
    const f16v8* __restrict__ wf = reinterpret_cast<const f16v8*>(wfrag);

    const int st_t = tid & 127;         // t index this thread stages (0..127)
    const int kpp  = tid >> 7;          // k-quad index 0..3 (k = 4*kpp..4*kpp+3)
    const int st_sw = (st_t >> 3) & 3;
    const int wr_base = 20 * st_t + 2 * (kpp & 1);
    const int s0 = ((0 + (kpp >> 1)) ^ st_sw) * 4;   // plane0 slot offset (dwords)
    const int s1 = ((2 + (kpp >> 1)) ^ st_sw) * 4;   // plane1 slot offset

    f32x16 accA[4] = {};   // [tsub] hh
    f32x16 accB[4] = {};   // [tsub] cross (scaled 2^11)
    f16v8  af[2][2];       // [buf][plane]
    float  xq[4][4];       // [slot][r] 4-deep x prefetch queue

    auto loadX = [&](int kc, float (&xd)[4]) {
        const float* px = xb + (size_t)(kc * 16 + 4 * kpp) * kT + tg0 + st_t;
#pragma unroll
        for (int r = 0; r < 4; ++r) xd[r] = px[(size_t)r * kT];
    };
    auto loadA = [&](int kc, f16v8 (&ad)[2]) {
#pragma unroll
        for (int pp = 0; pp < 2; ++pp)
            ad[pp] = wf[(size_t)((kc * 8 + osg) * 2 + pp) * 64 + lane];
    };
    auto stage = [&](int buf, const float (&xd)[4]) {
        auto h01 = __builtin_amdgcn_cvt_pkrtz(xd[0], xd[1]);   // RTZ pack
        auto h23 = __builtin_amdgcn_cvt_pkrtz(xd[2], xd[3]);
        auto l01 = __builtin_amdgcn_cvt_pkrtz((xd[0] - (float)h01[0]) * 2048.0f,
                                              (xd[1] - (float)h01[1]) * 2048.0f);
        auto l23 = __builtin_amdgcn_cvt_pkrtz((xd[2] - (float)h23[0]) * 2048.0f,
                                              (xd[3] - (float)h23[1]) * 2048.0f);
        h16v4 hv, lv;
        hv[0] = h01[0]; hv[1] = h01[1]; hv[2] = h23[0]; hv[3] = h23[1];
        lv[0] = l01[0]; lv[1] = l01[1]; lv[2] = l23[0]; lv[3] = l23[1];
        *reinterpret_cast<h16v4*>(&Bd[buf][wr_base + s0]) = hv;   // ds_write_b64
        *reinterpret_cast<h16v4*>(&Bd[buf][wr_base + s1]) = lv;
    };
    auto domfma = [&](int buf, const f16v8 (&ad)[2]) {
        __builtin_amdgcn_s_setprio(1);
#pragma unroll
        for (int s = 0; s < 4; ++s) {
            const int t = s * 32 + n;
            const int sw = (t >> 3) & 3;
            const f16v8 bh = *reinterpret_cast<const f16v8*>(&Bd[buf][20 * t + 4 * ((0 + q) ^ sw)]);
            const f16v8 bl = *reinterpret_cast<const f16v8*>(&Bd[buf][20 * t + 4 * ((2 + q) ^ sw)]);
            accA[s] = __builtin_amdgcn_mfma_f32_32x32x16_f16(ad[0], bh, accA[s], 0, 0, 0);
            accB[s] = __builtin_amdgcn_mfma_f32_32x32x16_f16(ad[0], bl, accB[s], 0, 0, 0);
            accB[s] = __builtin_amdgcn_mfma_f32_32x32x16_f16(ad[1], bh, accB[s], 0, 0, 0);
        }
        __builtin_amdgcn_s_setprio(0);
    };

    // prologue: fill 4-deep x queue, A buf 0, stage chunks 0 and 1
    loadX(0, xq[0]); loadX(1, xq[1]); loadX(2, xq[2]); loadX(3, xq[3]);
    loadA(0, af[0]);
    stage(0, xq[0]);
    stage(1, xq[1]);
    asm volatile("s_waitcnt lgkmcnt(0)\n\ts_barrier" ::: "memory");

    for (int kc4 = 0; kc4 < 8; ++kc4) {
#pragma unroll
        for (int u = 0; u < 4; ++u) {
            const int kc = kc4 * 4 + u;
            // all buffer/slot indices below are compile-time: kc&3==u, kc&1==u&1
            if (kc < 31) loadA(kc + 1, af[(u + 1) & 1]);
            if (kc < 30) stage((u + 2) & 3, xq[(u + 2) & 3]);   // stage chunk kc+2
            if (kc < 28) loadX(kc + 4, xq[u]);                  // refill slot
            domfma(u, af[u & 1]);
            if (u & 1)  // one barrier per 2 chunks; global loads stay in flight
                asm volatile("s_waitcnt lgkmcnt(0)\n\ts_barrier" ::: "memory");
        }
    }

    // ---- epilogue: combine planes, BN affine, store yt[b][o][t] (no LDS) ----
    // C/D: col(t)=lane&31, row(o)=(reg&3)+8*(reg>>2)+4*(lane>>5)
#pragma unroll
    for (int s = 0; s < 4; ++s) {
        const f32x16 v = accA[s] + accB[s] * 4.8828125e-4f;   // + cross/2^11
        const size_t t = (size_t)tg0 + s * 32 + n;
#pragma unroll
        for (int g = 0; g < 4; ++g) {
            const int og = osg * 32 + g * 8 + q * 4;
            const f32x4 sv = *reinterpret_cast<const f32x4*>(sarr + og);
            const f32x4 mv = *reinterpret_cast<const f32x4*>(rmean + og);
            const f32x4 bv = *reinterpret_cast<const f32x4*>(beta + og);
#pragma unroll
            for (int r2 = 0; r2 < 4; ++r2) {
                const int o = og + r2;
                // exact /32 un-scale, then BN (same per-element op order as before)
                const float val = (v[4 * g + r2] * 0.03125f - mv[r2]) * sv[r2] + bv[r2];
                yt[(((size_t)b << 8) + (size_t)o) * 1024 + t] = val;
            }
        }
    }
}

// ---- LIF: one wave per (b, 64-o slice); yt[b][o][t] rows are contiguous ----
// Each lane owns one o-chain and reads float4 over t (16-quad static prefetch
// queue, 16 KiB/wave in flight). Bit-exact fp32 recurrence vs reference.
__global__ __launch_bounds__(64)
void lif_kernel(const float* __restrict__ yt, float* __restrict__ out) {
    const int b = blockIdx.x >> 2;
    const int o = ((blockIdx.x & 3) << 6) + threadIdx.x;
    const f32x4* __restrict__ row =
        reinterpret_cast<const f32x4*>(yt) + (((size_t)b << 8) + (size_t)o) * 256;
    float v = 0.f;
    int cnt = 0;
    f32x4 qb[16];
#pragma unroll
    for (int u = 0; u < 16; ++u) qb[u] = row[u];
    for (int jj = 0; jj < 15; ++jj) {
#pragma unroll
        for (int u = 0; u < 16; ++u) {
            const f32x4 cv = qb[u];
            qb[u] = row[jj * 16 + u + 16];   // distance-16 prefetch, static slot
#pragma unroll
            for (int e = 0; e < 4; ++e) {
                v = v + (cv[e] - v) * 0.5f;             // bit-exact reference recurrence
                if (v - 1.0f >= 0.0f) { ++cnt; v = 0.f; }
            }
        }
    }
#pragma unroll
    for (int u = 0; u < 16; ++u) {
        const f32x4 cv = qb[u];
#pragma unroll
        for (int e = 0; e < 4; ++e) {
            v = v + (cv[e] - v) * 0.5f;
            if (v - 1.0f >= 0.0f) { ++cnt; v = 0.f; }
        }
    }
    out[((size_t)b << 8) + o] = (float)cnt * (1.0f / 1024.0f);
}

// ---- fallback (round-1 fp32 fused path, unchanged) ----
namespace fb {
constexpr int kOTile = 32, kTTile = 128, kCc = 64;
constexpr int kNtt = kT / kTTile, kNcc = kCin / kCc, kYPad = 132;
}

__global__ void wt_transpose_kernel(const float* __restrict__ W, float* __restrict__ Wt) {
    int idx = blockIdx.x * 256 + threadIdx.x;
    int c = idx >> 8, o = idx & 255;
    Wt[idx] = W[o * kCin + c];
}

__global__ __launch_bounds__(256, 2)
void snn_fused_kernel(const float* __restrict__ x, const float* __restrict__ Wt,
                      const float* __restrict__ gamma, const float* __restrict__ beta,
                      const float* __restrict__ rmean, const float* __restrict__ rvar,
                      float* __restrict__ out) {
    using namespace fb;
    __shared__ float xs[kCc][kTTile];
    __shared__ float ws[kCc][kOTile];
    __shared__ float ytile[kOTile][kYPad];
    __shared__ float sarr[kOTile], barr[kOTile], marr[kOTile], vstate[kOTile];
    __shared__ int scnt[kOTile];
    const int tid = threadIdx.x, tx = tid & 31, ty = tid >> 5;
    const int b = blockIdx.y, o_blk = blockIdx.x * kOTile;
    if (tid < kOTile) {
        const int o = o_blk + tid;
        const double dinv = 1.0 / sqrt((double)rvar[o] + 1e-5);
        sarr[tid] = (float)(dinv * (double)gamma[o]);
        barr[tid] = beta[o]; marr[tid] = rmean[o];
        vstate[tid] = 0.0f; scnt[tid] = 0;
    }
    __syncthreads();
    const float* xb = x + (size_t)b * kCin * kT;
    for (int tt = 0; tt < kNtt; ++tt) {
        float acc[4][4];
#pragma unroll
        for (int i = 0; i < 4; ++i)
#pragma unroll
            for (int j = 0; j < 4; ++j) acc[i][j] = 0.0f;
        const int t0 = tt * kTTile;
        for (int cc = 0; cc < kNcc; ++cc) {
#pragma unroll
            for (int k = 0; k < 8; ++k) {
                const int f = tid + 256 * k;
                const int c = f >> 5, tq = f & 31;
                *reinterpret_cast<float4*>(&xs[c][tq * 4]) = *reinterpret_cast<const float4*>(
                    xb + (size_t)(cc * kCc + c) * kT + t0 + tq * 4);
            }
#pragma unroll
            for (int k = 0; k < 2; ++k) {
                const int f = tid + 256 * k;
                const int c = f >> 3, oq = f & 7;
                *reinterpret_cast<float4*>(&ws[c][oq * 4]) = *reinterpret_cast<const float4*>(
                    Wt + (size_t)(cc * kCc + c) * kCout + o_blk + oq * 4);
            }
            __syncthreads();
#pragma unroll 8
            for (int c = 0; c < kCc; ++c) {
                const float4 xv = *reinterpret_cast<const float4*>(&xs[c][tx * 4]);
                const float4 wv = *reinterpret_cast<const float4*>(&ws[c][ty * 4]);
                const float xf[4] = {xv.x, xv.y, xv.z, xv.w};
                const float wf4[4] = {wv.x, wv.y, wv.z, wv.w};
#pragma unroll
                for (int i = 0; i < 4; ++i)
#pragma unroll
                    for (int j = 0; j < 4; ++j) acc[i][j] += wf4[i] * xf[j];
            }
            __syncthreads();
        }
#pragma unroll
        for (int i = 0; i < 4; ++i) {
            const int o = ty * 4 + i;
            const float s = sarr[o], bb2 = barr[o], m = marr[o];
#pragma unroll
            for (int j = 0; j < 4; ++j) ytile[o][tx * 4 + j] = (acc[i][j] - m) * s + bb2;
        }
        __syncthreads();
        if (tid < kOTile) {
            float vv = vstate[tid];
            int cnt = 0;
#pragma unroll 4
            for (int t = 0; t < kTTile; ++t) {
                const float yv = ytile[tid][t];
                vv = vv + (yv - vv) * 0.5f;
                if (vv - 1.0f >= 0.0f) { cnt++; vv = 0.0f; }
            }
            vstate[tid] = vv; scnt[tid] += cnt;
        }
        __syncthreads();
    }
    if (tid < kOTile) out[b * kCout + o_blk + tid] = (float)scnt[tid] * (1.0f / 1024.0f);
}

extern "C" void kernel_launch(void* const* d_in, const int* in_sizes, int n_in,
                              void* d_out, int out_size, void* d_ws, size_t ws_size,
                              hipStream_t stream) {
    const float* x     = (const float*)d_in[0];
    const float* W     = (const float*)d_in[1];
    const float* gamma = (const float*)d_in[2];
    const float* beta  = (const float*)d_in[3];
    const float* rmean = (const float*)d_in[4];
    const float* rvar  = (const float*)d_in[5];
    float* out = (float*)d_out;

    if (ws_size >= kWsNeed) {
        float* yt    = (float*)d_ws;
        f16*   wfrag = (f16*)((char*)d_ws + kYBytes);
        float* sarr  = (float*)((char*)d_ws + kYBytes + kWfragBytes);
        wsplit16_kernel<<<dim3(32, 8, 2), 64, 0, stream>>>(W, gamma, rvar, wfrag, sarr);
        gemm_f16_kernel<<<dim3(8, 64), 512, 0, stream>>>(x, wfrag, sarr, rmean, beta, yt);
        lif_kernel<<<256, 64, 0, stream>>>(yt, out);
    } else {
        float* Wt = (float*)d_ws;
        wt_transpose_kernel<<<(kCin * kCout) / 256, 256, 0, stream>>>(W, Wt);
        snn_fused_kernel<<<dim3(kCout / fb::kOTile, kB), 256, 0, stream>>>(
            x, Wt, gamma, beta, rmean, rvar, out);
    }
}